// Round 3
// baseline (543.743 us; speedup 1.0000x reference)
//
#include <hip/hip_runtime.h>
#include <hip/hip_bf16.h>

#define IN_DIM 300
#define MEM    150
#define GP     160
#define KX     300
#define KXP    320
#define KH     160
#define NLEAF  65536
#define NINT   21845   // NTOT - NLEAF
#define NTOT   87381
#define DEPTH  9

static const int SIZES[DEPTH] = {65536,16384,4096,1024,256,64,16,4,1};
static const int OFF[DEPTH]   = {0,65536,81920,86016,87040,87296,87360,87376,87380};

typedef __attribute__((ext_vector_type(8))) short short8;
typedef __attribute__((ext_vector_type(4))) float f32x4;
typedef unsigned short u16;

__device__ __forceinline__ float sigf(float x) { return 1.0f / (1.0f + __expf(-x)); }
__device__ __forceinline__ float tanhf_fast(float x) {
    float e = __expf(2.0f * x);
    return 1.0f - 2.0f / (e + 1.0f);
}
__device__ __forceinline__ u16 f2bf(float f) {
    union { float f; unsigned u; } v; v.f = f;
    unsigned r = v.u + 0x7FFF + ((v.u >> 16) & 1);
    return (u16)(r >> 16);
}
__device__ __forceinline__ float bf2f(u16 u) {
    union { unsigned u; float f; } v; v.u = ((unsigned)u) << 16; return v.f;
}
// load 2 adjacent bf16 (4B-aligned) -> 2 floats
__device__ __forceinline__ void ld2(const u16* p, float& a, float& b) {
    unsigned v = *(const unsigned*)p;
    union { unsigned u; float f; } x, y;
    x.u = v << 16; y.u = v & 0xffff0000u;
    a = x.f; b = y.f;
}
__device__ __forceinline__ unsigned pk2(float a, float b) {
    return (unsigned)f2bf(a) | ((unsigned)f2bf(b) << 16);
}
// async global->LDS, 16 B per lane; lds base must be wave-uniform
__device__ __forceinline__ void gl2lds16(const u16* g, u16* l) {
    __builtin_amdgcn_global_load_lds(
        (const __attribute__((address_space(1))) unsigned int*)g,
        (__attribute__((address_space(3))) unsigned int*)l,
        16, 0, 0);
}

// ---------------- weight packing ------------------------------------------------
// W4xT   640x320 rows [i|f|u|o] (out-col major, k contig) -> internal x-proj, bias b4x = b_x
// WxiuoT 512x320 rows [i|u|o|0]                          -> leaf x-proj, bias = b_x + b_h
// WfhT   256x160                                          -> f-gate child GEMM, bias b_fh
// WiuohT 512x160 rows [i|u|o|0]                           -> Hsum GEMM, bias = b_h(iuo)
__global__ void pack_weights(const float* __restrict__ Wix, const float* __restrict__ Wfx,
                             const float* __restrict__ Wux, const float* __restrict__ Wox,
                             const float* __restrict__ bix, const float* __restrict__ bfx,
                             const float* __restrict__ bux, const float* __restrict__ box,
                             const float* __restrict__ Wih, const float* __restrict__ Wfh,
                             const float* __restrict__ Wuh, const float* __restrict__ Woh,
                             const float* __restrict__ bfh,
                             const float* __restrict__ bih, const float* __restrict__ buh,
                             const float* __restrict__ boh,
                             u16* __restrict__ W4xT, u16* __restrict__ WxiuoT,
                             u16* __restrict__ WfhT, u16* __restrict__ WiuohT,
                             float* __restrict__ b4x, float* __restrict__ bleaf,
                             float* __restrict__ bfhp, float* __restrict__ biuoh)
{
    int stride = gridDim.x * blockDim.x;
    int tid = blockIdx.x * blockDim.x + threadIdx.x;
    for (int idx = tid; idx < 640 * KXP; idx += stride) {
        int c = idx / KXP, k = idx - c * KXP;
        int g = c / GP, j = c - g * GP;
        const float* W = (g == 0) ? Wix : (g == 1) ? Wfx : (g == 2) ? Wux : Wox;
        W4xT[idx] = (j < MEM && k < KX) ? f2bf(W[k * MEM + j]) : (u16)0;
    }
    for (int idx = tid; idx < 512 * KXP; idx += stride) {
        int c = idx / KXP, k = idx - c * KXP;
        int g = c / GP, j = c - g * GP;
        const float* W = (g == 0) ? Wix : (g == 1) ? Wux : Wox;
        WxiuoT[idx] = (g < 3 && j < MEM && k < KX) ? f2bf(W[k * MEM + j]) : (u16)0;
    }
    for (int idx = tid; idx < 256 * KH; idx += stride) {
        int c = idx / KH, k = idx - c * KH;
        WfhT[idx] = (c < MEM && k < MEM) ? f2bf(Wfh[k * MEM + c]) : (u16)0;
    }
    for (int idx = tid; idx < 512 * KH; idx += stride) {
        int c = idx / KH, k = idx - c * KH;
        int g = c / GP, j = c - g * GP;
        const float* W = (g == 0) ? Wih : (g == 1) ? Wuh : Woh;
        WiuohT[idx] = (g < 3 && j < MEM && k < MEM) ? f2bf(W[k * MEM + j]) : (u16)0;
    }
    for (int idx = tid; idx < 640; idx += stride) {
        int g = idx / GP, j = idx - g * GP;
        const float* b = (g == 0) ? bix : (g == 1) ? bfx : (g == 2) ? bux : box;
        b4x[idx] = (j < MEM) ? b[j] : 0.0f;
    }
    for (int idx = tid; idx < 512; idx += stride) {
        int g = idx / GP, j = idx - g * GP;
        float v = 0.0f;
        if (g < 3 && j < MEM) {
            const float* bx = (g == 0) ? bix : (g == 1) ? bux : box;
            const float* bh = (g == 0) ? bih : (g == 1) ? buh : boh;
            v = bx[j] + bh[j];
        }
        bleaf[idx] = v;
        float v2 = 0.0f;
        if (g < 3 && j < MEM) {
            const float* bh = (g == 0) ? bih : (g == 1) ? buh : boh;
            v2 = bh[j];
        }
        biuoh[idx] = v2;
    }
    for (int idx = tid; idx < 256; idx += stride)
        bfhp[idx] = (idx < MEM) ? bfh[idx] : 0.0f;
}

// ---------------- embs fp32 -> bf16, K padded 300->320 --------------------------
__global__ void cvt_embs(const float* __restrict__ E, u16* __restrict__ Abf)
{
    int i8 = blockIdx.x * 256 + threadIdx.x;
    const int CH = KXP / 8;  // 40 chunks per row
    if (i8 >= NTOT * CH) return;
    int r = i8 / CH, c8 = (i8 - r * CH) * 8;
    u16 v[8];
    if (c8 + 8 <= KX) {
        const float4* p = (const float4*)(E + (size_t)r * KX + c8);
        float4 f0 = p[0], f1 = p[1];
        v[0] = f2bf(f0.x); v[1] = f2bf(f0.y); v[2] = f2bf(f0.z); v[3] = f2bf(f0.w);
        v[4] = f2bf(f1.x); v[5] = f2bf(f1.y); v[6] = f2bf(f1.z); v[7] = f2bf(f1.w);
    } else {
        #pragma unroll
        for (int j = 0; j < 8; ++j) {
            int c = c8 + j;
            v[j] = (c < KX) ? f2bf(E[(size_t)r * KX + c]) : (u16)0;
        }
    }
    *(short8*)(Abf + (size_t)r * KXP + c8) = *(short8*)v;
}

// ---------------- m97-style MFMA GEMM with global_load_lds ----------------------
// C[M x Ncols] = A[M x K] @ BT^T + bias.  A,BT bf16, K contiguous, K % 32 == 0,
// rows 16B-aligned. BT has >= colTiles*128 rows (zero-padded). 128x128 tile,
// BK=32, 4 waves of 64x64. XCD swizzle: all colTiles of a row-tile land on the
// same XCD (bid%8) for L2 reuse of A.
__global__ __launch_bounds__(256) void gemm_glds(
    const u16* __restrict__ A, int M, int K,
    const u16* __restrict__ BT, const float* __restrict__ bias,
    u16* __restrict__ Cout, int CP, int Ncols,
    int rowTiles, int colTiles)
{
    __shared__ __align__(16) u16 As[128 * 32];
    __shared__ __align__(16) u16 Bs[128 * 32];
    int bid = blockIdx.x;
    int grp = bid / (8 * colTiles);
    int rem = bid - grp * 8 * colTiles;
    int xt = grp * 8 + (rem & 7);
    int ct = rem >> 3;
    if (xt >= rowTiles) return;
    const int m0 = xt * 128, n0 = ct * 128;
    const int t = threadIdx.x;
    const int w = t >> 6, l = t & 63;
    const int l15 = l & 15, q = l >> 4;
    const int wm = (w & 1) * 64, wn = (w >> 1) * 64;

    // staging: wave w stages chunks {2w, 2w+1} (16 rows each) of both tiles.
    // lane l -> row (l>>2) within chunk, k-seg (l&3)*8. LDS layout: row-major,
    // 32 elems/row, chunk c at offset c*512 elems (lane*16B contiguous).
    const int srow0 = w * 32 + (l >> 2);
    const int srow1 = srow0 + 16;
    const int skk = (l & 3) * 8;
    int ar0 = m0 + srow0; if (ar0 >= M) ar0 = M - 1;
    int ar1 = m0 + srow1; if (ar1 >= M) ar1 = M - 1;
    const u16* Ab0 = A + (size_t)ar0 * K + skk;
    const u16* Ab1 = A + (size_t)ar1 * K + skk;
    const u16* Bb0 = BT + (size_t)(n0 + srow0) * K + skk;
    const u16* Bb1 = BT + (size_t)(n0 + srow1) * K + skk;
    u16* Asd0 = As + (w * 2) * 512;
    u16* Asd1 = As + (w * 2 + 1) * 512;
    u16* Bsd0 = Bs + (w * 2) * 512;
    u16* Bsd1 = Bs + (w * 2 + 1) * 512;

    f32x4 acc[4][4];
    #pragma unroll
    for (int i = 0; i < 4; ++i)
        #pragma unroll
        for (int j = 0; j < 4; ++j)
            acc[i][j] = (f32x4){0.f, 0.f, 0.f, 0.f};

    const int kiters = K >> 5;
    for (int kt = 0; kt < kiters; ++kt) {
        const int k0 = kt << 5;
        gl2lds16(Ab0 + k0, Asd0);
        gl2lds16(Ab1 + k0, Asd1);
        gl2lds16(Bb0 + k0, Bsd0);
        gl2lds16(Bb1 + k0, Bsd1);
        __syncthreads();
        short8 a[4], b[4];
        #pragma unroll
        for (int i = 0; i < 4; ++i)
            a[i] = *(const short8*)&As[(wm + i * 16 + l15) * 32 + q * 8];
        #pragma unroll
        for (int j = 0; j < 4; ++j)
            b[j] = *(const short8*)&Bs[(wn + j * 16 + l15) * 32 + q * 8];
        #pragma unroll
        for (int i = 0; i < 4; ++i)
            #pragma unroll
            for (int j = 0; j < 4; ++j)
                acc[i][j] = __builtin_amdgcn_mfma_f32_16x16x32_bf16(a[i], b[j], acc[i][j], 0, 0, 0);
        __syncthreads();
    }

    float bj[4];
    #pragma unroll
    for (int j = 0; j < 4; ++j) bj[j] = bias[n0 + wn + j * 16 + l15];
    #pragma unroll
    for (int i = 0; i < 4; ++i) {
        #pragma unroll
        for (int r = 0; r < 4; ++r) {
            int grow = m0 + wm + i * 16 + q * 4 + r;
            if (grow < M) {
                u16* crow = Cout + (size_t)grow * CP;
                #pragma unroll
                for (int j = 0; j < 4; ++j) {
                    int col = n0 + wn + j * 16 + l15;
                    if (col < Ncols) crow[col] = f2bf(acc[i][j][r] + bj[j]);
                }
            }
        }
    }
}

// ---------------- leaf elementwise (biases pre-folded into GEMM) ---------------
__global__ void leaf_ew(const u16* __restrict__ PGleaf,
                        float* __restrict__ out, float* __restrict__ C,
                        u16* __restrict__ Hbf)
{
    int idx = blockIdx.x * 256 + threadIdx.x;   // NLEAF * 80
    if (idx >= NLEAF * 80) return;
    int n = idx / 80, mm = (idx - n * 80) * 2;
    if (mm >= MEM) { *(unsigned*)(Hbf + (size_t)n * KH + mm) = 0; return; }
    const u16* row = PGleaf + (size_t)n * 480;
    float i0, i1, u0, u1, o0, o1;
    ld2(row + mm, i0, i1);
    ld2(row + GP + mm, u0, u1);
    ld2(row + 2 * GP + mm, o0, o1);
    float c0 = sigf(i0) * tanhf_fast(u0);
    float c1 = sigf(i1) * tanhf_fast(u1);
    float h0 = sigf(o0) * tanhf_fast(c0);
    float h1 = sigf(o1) * tanhf_fast(c1);
    size_t b = (size_t)n * MEM + mm;
    *(float2*)(out + b) = (float2){h0, h1};
    *(float2*)(C + b) = (float2){c0, c1};
    *(unsigned*)(Hbf + (size_t)n * KH + mm) = pk2(h0, h1);
}

// ---------------- per-parent child-h sum (from fp32 h), bf16 out ---------------
__global__ void hsum_k(const float* __restrict__ Hprev, u16* __restrict__ Hs, int n)
{
    int idx = blockIdx.x * 256 + threadIdx.x;   // n * 80
    if (idx >= n * 80) return;
    int nn = idx / 80, mm = (idx - nn * 80) * 2;
    unsigned v = 0;
    if (mm < MEM) {
        float s0 = 0.f, s1 = 0.f;
        #pragma unroll
        for (int k = 0; k < 4; ++k) {
            float2 hv = *(const float2*)(Hprev + (size_t)(4 * nn + k) * MEM + mm);
            s0 += hv.x; s1 += hv.y;
        }
        v = pk2(s0, s1);
    }
    *(unsigned*)(Hs + (size_t)nn * KH + mm) = v;
}

// ---------------- internal-level elementwise ------------------------------------
__global__ void level_ew(const u16* __restrict__ Pint,   // this level's x rows, pitch 640
                         const u16* __restrict__ Gf,     // per-child f proj, pitch 160
                         const u16* __restrict__ Gsum,   // iuo proj of hsum, pitch 480
                         const float* __restrict__ Cprev,
                         float* __restrict__ outRow, float* __restrict__ Crow,
                         u16* __restrict__ HbfRow, int n)
{
    int idx = blockIdx.x * 256 + threadIdx.x;   // n * 80
    if (idx >= n * 80) return;
    int nn = idx / 80, mm = (idx - nn * 80) * 2;
    if (mm >= MEM) { *(unsigned*)(HbfRow + (size_t)nn * KH + mm) = 0; return; }
    const u16* xr = Pint + (size_t)nn * 640;
    const u16* gs = Gsum + (size_t)nn * 480;
    float a0, a1, g0, g1;
    ld2(xr + mm, a0, a1);            ld2(gs + mm, g0, g1);
    float ip0 = a0 + g0, ip1 = a1 + g1;
    float fx0, fx1;
    ld2(xr + GP + mm, fx0, fx1);
    ld2(xr + 2 * GP + mm, a0, a1);   ld2(gs + GP + mm, g0, g1);
    float up0 = a0 + g0, up1 = a1 + g1;
    ld2(xr + 3 * GP + mm, a0, a1);   ld2(gs + 2 * GP + mm, g0, g1);
    float op0 = a0 + g0, op1 = a1 + g1;
    float fc0 = 0.f, fc1 = 0.f;
    #pragma unroll
    for (int k = 0; k < 4; ++k) {
        float gf0, gf1;
        ld2(Gf + (size_t)(4 * nn + k) * KH + mm, gf0, gf1);
        float2 cv = *(const float2*)(Cprev + (size_t)(4 * nn + k) * MEM + mm);
        fc0 += sigf(fx0 + gf0) * cv.x;
        fc1 += sigf(fx1 + gf1) * cv.y;
    }
    float c0 = sigf(ip0) * tanhf_fast(up0) + fc0;
    float c1 = sigf(ip1) * tanhf_fast(up1) + fc1;
    float h0 = sigf(op0) * tanhf_fast(c0);
    float h1 = sigf(op1) * tanhf_fast(c1);
    size_t b = (size_t)nn * MEM + mm;
    *(float2*)(outRow + b) = (float2){h0, h1};
    *(float2*)(Crow + b) = (float2){c0, c1};
    *(unsigned*)(HbfRow + (size_t)nn * KH + mm) = pk2(h0, h1);
}

extern "C" void kernel_launch(void* const* d_in, const int* in_sizes, int n_in,
                              void* d_out, int out_size, void* d_ws, size_t ws_size,
                              hipStream_t stream)
{
    (void)in_sizes; (void)n_in; (void)out_size;
    const float* embs = (const float*)d_in[0];
    const float* Wix = (const float*)d_in[1];  const float* bix = (const float*)d_in[2];
    const float* Wfx = (const float*)d_in[3];  const float* bfx = (const float*)d_in[4];
    const float* Wux = (const float*)d_in[5];  const float* bux = (const float*)d_in[6];
    const float* Wox = (const float*)d_in[7];  const float* box = (const float*)d_in[8];
    const float* Wih = (const float*)d_in[9];  const float* bih = (const float*)d_in[10];
    const float* Wfh = (const float*)d_in[11]; const float* bfh = (const float*)d_in[12];
    const float* Wuh = (const float*)d_in[13]; const float* buh = (const float*)d_in[14];
    const float* Woh = (const float*)d_in[15]; const float* boh = (const float*)d_in[16];
    float* out = (float*)d_out;

    char* p = (char*)d_ws;
    auto alloc = [&](size_t bytes) -> char* {
        char* r = p;
        p += (bytes + 255) & ~(size_t)255;
        return r;
    };
    u16*   PGleaf = (u16*)alloc((size_t)NLEAF * 480 * 2);      // 63.0 MB
    u16*   PGint  = (u16*)alloc((size_t)NINT * 640 * 2);       // 28.0 MB
    u16*   Hbf    = (u16*)alloc((size_t)NTOT * KH * 2);        // 28.0 MB
    char*  AC     = alloc((size_t)NTOT * KXP * 2);             // 55.9 MB (Abf | C)
    u16*   W4xT   = (u16*)alloc((size_t)640 * KXP * 2);
    u16*   WxiuoT = (u16*)alloc((size_t)512 * KXP * 2);
    u16*   WfhT   = (u16*)alloc((size_t)256 * KH * 2);
    u16*   WiuohT = (u16*)alloc((size_t)512 * KH * 2);
    float* b4x    = (float*)alloc(640 * 4);
    float* bleaf  = (float*)alloc(512 * 4);
    float* bfhp   = (float*)alloc(256 * 4);
    float* biuoh  = (float*)alloc(512 * 4);
    if ((size_t)(p - (char*)d_ws) > ws_size) return;
    u16*   Abf = (u16*)AC;
    float* C   = (float*)AC;      // alive only after x-proj GEMMs finish reading Abf
    // level scratch aliased into PGleaf (dead after leaf_ew): 42.0 MB <= 63.0 MB
    u16* Gf   = PGleaf;                               // <= 65536*160
    u16* Gsum = PGleaf + (size_t)NLEAF * KH;          // <= 16384*480
    u16* Hsum = Gsum + (size_t)16384 * 480;           // <= 16384*160

    pack_weights<<<96, 256, 0, stream>>>(Wix, Wfx, Wux, Wox, bix, bfx, bux, box,
                                         Wih, Wfh, Wuh, Woh, bfh, bih, buh, boh,
                                         W4xT, WxiuoT, WfhT, WiuohT,
                                         b4x, bleaf, bfhp, biuoh);
    cvt_embs<<<(NTOT * (KXP / 8) + 255) / 256, 256, 0, stream>>>(embs, Abf);

    // leaf x-proj (i,u,o; biases b_x+b_h folded): M=65536, rowTiles=512, colTiles=4
    gemm_glds<<<(512 / 8) * 8 * 4, 256, 0, stream>>>(
        Abf, NLEAF, KXP, WxiuoT, bleaf, PGleaf, 480, 480, 512, 4);
    // internal x-proj (i,f,u,o; bias b_x): M=21845, rowTiles=171, colTiles=5
    gemm_glds<<<((171 + 7) / 8) * 8 * 5, 256, 0, stream>>>(
        Abf + (size_t)NLEAF * KXP, NINT, KXP, W4xT, b4x, PGint, 640, 640, 171, 5);

    leaf_ew<<<(NLEAF * 80 + 255) / 256, 256, 0, stream>>>(PGleaf, out, C, Hbf);

    for (int d = 1; d < DEPTH; ++d) {
        int n = SIZES[d], np = SIZES[d - 1];
        int offp = OFF[d - 1], off = OFF[d];
        hsum_k<<<(n * 80 + 255) / 256, 256, 0, stream>>>(out + (size_t)offp * MEM, Hsum, n);
        int rtf = (np + 127) / 128;
        gemm_glds<<<((rtf + 7) / 8) * 8 * 2, 256, 0, stream>>>(
            Hbf + (size_t)offp * KH, np, KH, WfhT, bfhp, Gf, 160, 160, rtf, 2);
        int rts = (n + 127) / 128;
        gemm_glds<<<((rts + 7) / 8) * 8 * 4, 256, 0, stream>>>(
            Hsum, n, KH, WiuohT, biuoh, Gsum, 480, 480, rts, 4);
        level_ew<<<(n * 80 + 255) / 256, 256, 0, stream>>>(
            PGint + (size_t)(off - NLEAF) * 640, Gf, Gsum,
            C + (size_t)offp * MEM,
            out + (size_t)off * MEM, C + (size_t)off * MEM,
            Hbf + (size_t)off * KH, n);
    }
}